// Round 11
// baseline (50.828 us; speedup 1.0000x reference)
//
#include <hip/hip_runtime.h>
#include <cstdint>

typedef unsigned long long u64;
typedef unsigned int u32;

#define DIM    10000
#define NCLS   100
#define BATCH  4096
#define F4ROW  2500          // float4s per input row
#define NCH    40            // 256-dim chunks per row (chunk 39 partial)

// Bit order (identical for q and am): chunk C covers dims [C*256, C*256+256);
// word j of chunk C, bit i <- dim C*256 + 4i + j (ballot lane i, float4 elem j).
// apT2 layout: [wpair = 2C + (j>>1)][class], .x = word j=0/2, .y = word j=1/3.
// Pad dims (>= DIM) give 0-bits on BOTH operands -> XOR contributes nothing.

// ---- pack am -> apT2 (VERBATIM rounds 7/10, known-correct) ----
__global__ __launch_bounds__(256) void pack_a_t(const float* __restrict__ a,
                                                ulonglong2* __restrict__ apT2) {
    const int lane = threadIdx.x & 63;
    const int r    = blockIdx.x * 4 + (threadIdx.x >> 6);   // class 0..99
    const float* row = a + (size_t)r * DIM;
    for (int C = 0; C < NCH; ++C) {
        const int d0 = C * 256 + lane * 4;
        float4 v = make_float4(0.f, 0.f, 0.f, 0.f);
        if (d0 < DIM) v = *(const float4*)(row + d0);
        const u64 b0 = __ballot(v.x > 0.5f);
        const u64 b1 = __ballot(v.y > 0.5f);
        const u64 b2 = __ballot(v.z > 0.5f);
        const u64 b3 = __ballot(v.w > 0.5f);
        if (lane < 2) {
            ulonglong2 u;
            u.x = lane ? b2 : b0;
            u.y = lane ? b3 : b1;
            apT2[(size_t)(2 * C + lane) * NCLS + r] = u;    // wpair = 2C+lane
        }
    }
}

// hamming for one full 256-dim chunk C (no bounds handling: C <= 38 is full)
__device__ __forceinline__ void do_chunk(const float* __restrict__ row,
                                         const ulonglong2* __restrict__ apT2,
                                         const int C, const int lane,
                                         const int clsA, const int clsB,
                                         u32& accA, u32& accB) {
    const float4 v = *(const float4*)(row + (size_t)(C * 64 + lane) * 4);
    const u64 b0 = __ballot(v.x > 0.5f);
    const u64 b1 = __ballot(v.y > 0.5f);
    const u64 b2 = __ballot(v.z > 0.5f);
    const u64 b3 = __ballot(v.w > 0.5f);
    const ulonglong2* wp0 = apT2 + (size_t)(2 * C) * NCLS;
    const ulonglong2* wp1 = wp0 + NCLS;
    const ulonglong2 aA0 = wp0[clsA];
    const ulonglong2 aA1 = wp1[clsA];
    const ulonglong2 aB0 = wp0[clsB];
    const ulonglong2 aB1 = wp1[clsB];
    accA += (u32)(__popcll(b0 ^ aA0.x) + __popcll(b1 ^ aA0.y) +
                  __popcll(b2 ^ aA1.x) + __popcll(b3 ^ aA1.y));
    accB += (u32)(__popcll(b0 ^ aB0.x) + __popcll(b1 ^ aB0.y) +
                  __popcll(b2 ^ aB1.x) + __popcll(b3 ^ aB1.y));
}

// ---- fused v3: 2 waves per row (half-row each), LDS combine ----
// block = 512 threads = 8 waves = 4 rows x 2 halves; grid = BATCH/4 = 1024.
// 8192 waves total = 32 waves/CU (2x round 10's occupancy).
__global__ __launch_bounds__(512) void fused_v3(const float* __restrict__ q,
                                                const ulonglong2* __restrict__ apT2,
                                                float* __restrict__ out) {
    __shared__ int part[4][128];
    const int lane = threadIdx.x & 63;
    const int wv   = threadIdx.x >> 6;                      // 0..7
    const int rloc = wv >> 1;                               // 0..3
    const int half = wv & 1;                                // 0: C<20, 1: C>=20
    const int r    = blockIdx.x * 4 + rloc;
    const float* row = q + (size_t)r * DIM;

    const int clsA = lane;
    const int clsB = 64 + (lane < NCLS - 64 ? lane : NCLS - 65);
    u32 accA = 0, accB = 0;

    if (half == 0) {
#pragma unroll 4
        for (int C = 0; C < 20; ++C)
            do_chunk(row, apT2, C, lane, clsA, clsB, accA, accB);
    } else {
#pragma unroll 4
        for (int C = 20; C < 39; ++C)
            do_chunk(row, apT2, C, lane, clsA, clsB, accA, accB);
        {   // chunk 39: dims 9984..9999 -> only lanes 0..3 in range
            const int idx  = 39 * 64 + lane;
            const int lidx = idx < F4ROW ? idx : F4ROW - 1;
            const float4 v = *(const float4*)(row + (size_t)lidx * 4);
            const bool ok  = idx < F4ROW;
            const u64 b0 = __ballot(ok && (v.x > 0.5f));
            const u64 b1 = __ballot(ok && (v.y > 0.5f));
            const u64 b2 = __ballot(ok && (v.z > 0.5f));
            const u64 b3 = __ballot(ok && (v.w > 0.5f));
            const ulonglong2* wp0 = apT2 + (size_t)(2 * 39) * NCLS;
            const ulonglong2* wp1 = wp0 + NCLS;
            const ulonglong2 aA0 = wp0[clsA];
            const ulonglong2 aA1 = wp1[clsA];
            const ulonglong2 aB0 = wp0[clsB];
            const ulonglong2 aB1 = wp1[clsB];
            accA += (u32)(__popcll(b0 ^ aA0.x) + __popcll(b1 ^ aA0.y) +
                          __popcll(b2 ^ aA1.x) + __popcll(b3 ^ aA1.y));
            accB += (u32)(__popcll(b0 ^ aB0.x) + __popcll(b1 ^ aB0.y) +
                          __popcll(b2 ^ aB1.x) + __popcll(b3 ^ aB1.y));
        }
    }

    if (half == 0) {
        part[rloc][lane] = (int)accA;
        if (lane < NCLS - 64) part[rloc][64 + lane] = (int)accB;
    }
    __syncthreads();
    if (half == 1) {
        float* orow = out + (size_t)r * NCLS;
        const int sA = part[rloc][lane] + (int)accA;
        orow[lane] = (float)(DIM - sA);                     // coalesced
        if (lane < NCLS - 64) {
            const int sB = part[rloc][64 + lane] + (int)accB;
            orow[64 + lane] = (float)(DIM - sB);
        }
    }
}

extern "C" void kernel_launch(void* const* d_in, const int* in_sizes, int n_in,
                              void* d_out, int out_size, void* d_ws, size_t ws_size,
                              hipStream_t stream) {
    const float* q = (const float*)d_in[0];   // [4096, 10000] f32 {0,1}
    const float* a = (const float*)d_in[1];   // [100, 10000]  f32 {0,1}
    float* out = (float*)d_out;               // [4096, 100]   f32

    // ws: apT2 only (80 wpairs * 100 classes * 16 B = 128,000 B)
    ulonglong2* apT2 = (ulonglong2*)d_ws;

    pack_a_t<<<25, 256, 0, stream>>>(a, apT2);
    fused_v3<<<BATCH / 4, 512, 0, stream>>>(q, apT2, out);
}

// Round 12
// 46.219 us; speedup vs baseline: 1.0997x; 1.0997x over previous
//
#include <hip/hip_runtime.h>
#include <cstdint>

typedef unsigned long long u64;
typedef unsigned int u32;

#define DIM    10000
#define NCLS   100
#define BATCH  4096
#define F4ROW  2500          // float4s per input row
#define NCH    40            // 256-dim chunks per row (chunk 39 partial)

// Bit order (identical for q and am): chunk C covers dims [C*256, C*256+256);
// word j of chunk C, bit i <- dim C*256 + 4i + j (ballot lane i, float4 elem j).
// apT2 layout: [wpair = 2C + (j>>1)][class], .x = word j=0/2, .y = word j=1/3.
// Pad dims (>= DIM) give 0-bits on BOTH operands -> XOR contributes nothing.

// ---- pack am -> apT2 (VERBATIM rounds 7/10/11, known-correct) ----
__global__ __launch_bounds__(256) void pack_a_t(const float* __restrict__ a,
                                                ulonglong2* __restrict__ apT2) {
    const int lane = threadIdx.x & 63;
    const int r    = blockIdx.x * 4 + (threadIdx.x >> 6);   // class 0..99
    const float* row = a + (size_t)r * DIM;
    for (int C = 0; C < NCH; ++C) {
        const int d0 = C * 256 + lane * 4;
        float4 v = make_float4(0.f, 0.f, 0.f, 0.f);
        if (d0 < DIM) v = *(const float4*)(row + d0);
        const u64 b0 = __ballot(v.x > 0.5f);
        const u64 b1 = __ballot(v.y > 0.5f);
        const u64 b2 = __ballot(v.z > 0.5f);
        const u64 b3 = __ballot(v.w > 0.5f);
        if (lane < 2) {
            ulonglong2 u;
            u.x = lane ? b2 : b0;
            u.y = lane ? b3 : b1;
            apT2[(size_t)(2 * C + lane) * NCLS + r] = u;    // wpair = 2C+lane
        }
    }
}

// ---- fused v4: block = 4 rows x 40 chunks; wave w does chunks [10w,10w+10)
// for ALL 4 rows -> each ap load amortized over 4 rows (ap bytes / 4).
// grid 1024 x 256 (16 waves/CU, same as v2 -> controlled A/B on traffic only).
__global__ __launch_bounds__(256) void fused_v4(const float* __restrict__ q,
                                                const ulonglong2* __restrict__ apT2,
                                                float* __restrict__ out) {
    __shared__ int part[4][4][128];                         // [wave][row][class]
    const int lane = threadIdx.x & 63;
    const int wv   = threadIdx.x >> 6;                      // 0..3 = chunk group
    const int r0   = blockIdx.x * 4;
    const int clsA = lane;
    const int clsB = 64 + (lane < NCLS - 64 ? lane : NCLS - 65);

    u32 accA[4] = {0, 0, 0, 0};
    u32 accB[4] = {0, 0, 0, 0};

    const int Cbeg = wv * 10;
    const int Cfull = (wv == 3) ? 39 : Cbeg + 10;           // chunk 39 handled apart

    for (int C = Cbeg; C < Cfull; ++C) {
        float4 v[4];
#pragma unroll
        for (int ri = 0; ri < 4; ++ri)                      // 4 independent 1 KB loads
            v[ri] = *(const float4*)(q + (size_t)(r0 + ri) * DIM
                                       + (size_t)(C * 64 + lane) * 4);
        const ulonglong2* wp0 = apT2 + (size_t)(2 * C) * NCLS;
        const ulonglong2* wp1 = wp0 + NCLS;
        const ulonglong2 aA0 = wp0[clsA];                   // shared by 4 rows
        const ulonglong2 aA1 = wp1[clsA];
        const ulonglong2 aB0 = wp0[clsB];
        const ulonglong2 aB1 = wp1[clsB];
#pragma unroll
        for (int ri = 0; ri < 4; ++ri) {
            const u64 b0 = __ballot(v[ri].x > 0.5f);        // wave-uniform words
            const u64 b1 = __ballot(v[ri].y > 0.5f);
            const u64 b2 = __ballot(v[ri].z > 0.5f);
            const u64 b3 = __ballot(v[ri].w > 0.5f);
            accA[ri] += (u32)(__popcll(b0 ^ aA0.x) + __popcll(b1 ^ aA0.y) +
                              __popcll(b2 ^ aA1.x) + __popcll(b3 ^ aA1.y));
            accB[ri] += (u32)(__popcll(b0 ^ aB0.x) + __popcll(b1 ^ aB0.y) +
                              __popcll(b2 ^ aB1.x) + __popcll(b3 ^ aB1.y));
        }
    }

    if (wv == 3) {                                          // chunk 39: partial
        const int C    = 39;
        const int idx  = C * 64 + lane;
        const int lidx = idx < F4ROW ? idx : F4ROW - 1;
        const bool ok  = idx < F4ROW;
        const ulonglong2* wp0 = apT2 + (size_t)(2 * C) * NCLS;
        const ulonglong2* wp1 = wp0 + NCLS;
        const ulonglong2 aA0 = wp0[clsA];
        const ulonglong2 aA1 = wp1[clsA];
        const ulonglong2 aB0 = wp0[clsB];
        const ulonglong2 aB1 = wp1[clsB];
#pragma unroll
        for (int ri = 0; ri < 4; ++ri) {
            const float4 v = *(const float4*)(q + (size_t)(r0 + ri) * DIM
                                                + (size_t)lidx * 4);
            const u64 b0 = __ballot(ok && (v.x > 0.5f));
            const u64 b1 = __ballot(ok && (v.y > 0.5f));
            const u64 b2 = __ballot(ok && (v.z > 0.5f));
            const u64 b3 = __ballot(ok && (v.w > 0.5f));
            accA[ri] += (u32)(__popcll(b0 ^ aA0.x) + __popcll(b1 ^ aA0.y) +
                              __popcll(b2 ^ aA1.x) + __popcll(b3 ^ aA1.y));
            accB[ri] += (u32)(__popcll(b0 ^ aB0.x) + __popcll(b1 ^ aB0.y) +
                              __popcll(b2 ^ aB1.x) + __popcll(b3 ^ aB1.y));
        }
    }

#pragma unroll
    for (int ri = 0; ri < 4; ++ri) {
        part[wv][ri][lane] = (int)accA[ri];
        if (lane < NCLS - 64) part[wv][ri][64 + lane] = (int)accB[ri];
    }
    __syncthreads();

    // combine 4 wave-partials -> 400 outputs, coalesced
    const int tid = threadIdx.x;
#pragma unroll
    for (int o = tid; o < 4 * NCLS; o += 256) {
        const int ri  = o / NCLS;
        const int cls = o - ri * NCLS;
        const int s = part[0][ri][cls] + part[1][ri][cls] +
                      part[2][ri][cls] + part[3][ri][cls];
        out[(size_t)(r0 + ri) * NCLS + cls] = (float)(DIM - s);
    }
}

extern "C" void kernel_launch(void* const* d_in, const int* in_sizes, int n_in,
                              void* d_out, int out_size, void* d_ws, size_t ws_size,
                              hipStream_t stream) {
    const float* q = (const float*)d_in[0];   // [4096, 10000] f32 {0,1}
    const float* a = (const float*)d_in[1];   // [100, 10000]  f32 {0,1}
    float* out = (float*)d_out;               // [4096, 100]   f32

    // ws: apT2 only (80 wpairs * 100 classes * 16 B = 128,000 B)
    ulonglong2* apT2 = (ulonglong2*)d_ws;

    pack_a_t<<<25, 256, 0, stream>>>(a, apT2);
    fused_v4<<<BATCH / 4, 256, 0, stream>>>(q, apT2, out);
}